// Round 1
// baseline (763.406 us; speedup 1.0000x reference)
//
#include <hip/hip_runtime.h>
#include <math.h>

// RNN-T transducer loss (forward only, mean reduction), three-phase:
//   Phase 0 (init_kernel): fill the diagonal-major lattice buffer with -INF
//     (invalid transitions stay -INF; phase 2 needs no boundary branches).
//   Phase 1 (gather_kernel): (b,t)-major gather — each wave reads the blank
//     and label log-probs of one (b,t) row-block, i.e. a contiguous 202 KB
//     window of the [B,T,U,512] tensor (vs. the old d-major mapping whose
//     waves sprayed 101 lines across 41 MB — DRAM-row/TLB hostile).
//     Writes an interleaved float4 lattice F[b][d][i] = {blk[2i],blk[2i+1],
//     emit[2i],emit[2i+1]}, so phase 2 needs ONE float4 load per lane per
//     diagonal.
//   Phase 2 (sweep_kernel): one wave per batch item; lane i owns columns
//     {2i, 2i+1}. Anti-diagonal wavefront with __shfl_up for the left
//     neighbor -- no LDS, no barriers. Ping-pong depth-8 register prefetch
//     (no ring copies).

#define BATCH 16
#define TMAX  200
#define UMAX  101                 // columns u = 0..100
#define VOC   512
#define NDIAG (TMAX + UMAX - 1)   // 300 diagonals
#define DEPTH 8
#define NEGINF (-INFINITY)

// float4 slots per diagonal row (covers 128 columns >= 101)
#define SLOTS 64

__device__ __forceinline__ float lse2(float a, float b) {
    float m = fmaxf(a, b);
    float r = m + __logf(__expf(a - m) + __expf(b - m));
    return (m == NEGINF) ? NEGINF : r;  // guard NaN from (-inf)-(-inf)
}

__global__ __launch_bounds__(256) void init_kernel(float4* __restrict__ F) {
    const size_t i = (size_t)blockIdx.x * 256 + threadIdx.x;
    F[i] = make_float4(NEGINF, NEGINF, NEGINF, NEGINF);
}

// F[b][d][i] = {blk[2i], blk[2i+1], emit[2i], emit[2i+1]} where
//   blk[u]  = lp[b, d-u-1, u,   BLANK]     (top transition into (d-u, u))
//   emit[u] = lp[b, d-u,   u-1, lab[u-1]]  (left transition into (d-u, u))
__global__ __launch_bounds__(128) void gather_kernel(
    const float* __restrict__ lp, const int* __restrict__ labels,
    float* __restrict__ F)
{
    const int t = blockIdx.x;
    const int b = blockIdx.y;
    const int u = threadIdx.x;
    if (u >= UMAX) return;

    const size_t rowbase = (((size_t)b * TMAX + t) * UMAX + u) * VOC;
    const int d = t + u + 1;                       // both writes hit diagonal d
    float* Fb = F + (size_t)b * NDIAG * (SLOTS * 4);

    // blank at (t,u) -> blk component of cell (d, u)
    if (d < NDIAG) {                               // only (t=199,u=100) fails
        const float vb = lp[rowbase];
        Fb[(size_t)d * (SLOTS * 4) + (u >> 1) * 4 + (u & 1)] = vb;
    }
    // label emit at (t,u) -> emit component of cell (d, u+1)
    if (u < UMAX - 1) {                            // d <= 299 guaranteed here
        const int lab = labels[b * (UMAX - 1) + u];
        const float ve = lp[rowbase + lab];
        const int uc = u + 1;
        Fb[(size_t)d * (SLOTS * 4) + (uc >> 1) * 4 + 2 + (uc & 1)] = ve;
    }
}

__global__ __launch_bounds__(64) void sweep_kernel(
    const float4* __restrict__ F, const float* __restrict__ lp,
    const int* __restrict__ Tarr, const int* __restrict__ Uarr,
    float* __restrict__ out)
{
    const int b    = blockIdx.x;
    const int lane = threadIdx.x;
    const int Tb   = Tarr[b];
    const int Ub   = Uarr[b];
    const int dmax = Tb - 1 + Ub;          // in [149, 299]

    const float4* rf = F + (size_t)b * NDIAG * SLOTS + lane;

    // alpha for columns c0 = 2*lane, c1 = 2*lane+1 on the previous diagonal
    float A0 = (lane == 0) ? 0.0f : NEGINF;  // alpha[0,0] = 0
    float A1 = NEGINF;

    float4 qa[DEPTH], qb[DEPTH];
#pragma unroll
    for (int j = 0; j < DEPTH; ++j)
        qa[j] = rf[(size_t)min(1 + j, dmax) * SLOTS];
#pragma unroll
    for (int j = 0; j < DEPTH; ++j)
        qb[j] = rf[(size_t)min(1 + DEPTH + j, dmax) * SLOTS];

    for (int dbase = 1; dbase <= dmax; dbase += 2 * DEPTH) {
#pragma unroll
        for (int j = 0; j < DEPTH; ++j) {
            if (dbase + j > dmax) break;            // block-uniform
            const float4 q = qa[j];
            // left neighbor of c0 lives in lane-1's c1 (previous diagonal)
            float Aup = __shfl_up(A1, 1);           // lane 0: q.z = -INF masks it
            float n0 = lse2(A0 + q.x, Aup + q.y * 0.0f + Aup * 0.0f + q.z + Aup);
            // (expanded below properly; see real code path)
            n0 = lse2(A0 + q.x, Aup + q.z);
            float n1 = lse2(A1 + q.y, A0 + q.w);
            A0 = n0; A1 = n1;
        }
#pragma unroll
        for (int j = 0; j < DEPTH; ++j)             // refill qa for dbase+16
            qa[j] = rf[(size_t)min(dbase + 2 * DEPTH + j, dmax) * SLOTS];
#pragma unroll
        for (int j = 0; j < DEPTH; ++j) {
            if (dbase + DEPTH + j > dmax) break;    // block-uniform
            const float4 q = qb[j];
            float Aup = __shfl_up(A1, 1);
            float n0 = lse2(A0 + q.x, Aup + q.z);
            float n1 = lse2(A1 + q.y, A0 + q.w);
            A0 = n0; A1 = n1;
        }
#pragma unroll
        for (int j = 0; j < DEPTH; ++j)             // refill qb for dbase+24
            qb[j] = rf[(size_t)min(dbase + 3 * DEPTH + j, dmax) * SLOTS];
    }

    // after diagonal dmax, column Ub holds alpha[Tb-1, Ub]
    if (lane == (Ub >> 1)) {
        float Af   = (Ub & 1) ? A1 : A0;
        float blkf = lp[(((size_t)b * TMAX + (Tb - 1)) * UMAX + Ub) * VOC];
        atomicAdd(out, -(Af + blkf) * (1.0f / BATCH));
    }
}

extern "C" void kernel_launch(void* const* d_in, const int* in_sizes, int n_in,
                              void* d_out, int out_size, void* d_ws, size_t ws_size,
                              hipStream_t stream) {
    const float* lp     = (const float*)d_in[0];
    const int*   labels = (const int*)d_in[1];
    const int*   Tarr   = (const int*)d_in[2];
    const int*   Uarr   = (const int*)d_in[3];
    float* out = (float*)d_out;

    float4* F = (float4*)d_ws;   // 16 * 300 * 64 float4 = 4.9 MB

    hipMemsetAsync(out, 0, sizeof(float), stream);  // harness poisons d_out

    const int n_f4 = BATCH * NDIAG * SLOTS;         // 307200
    init_kernel<<<n_f4 / 256, 256, 0, stream>>>(F);

    dim3 g1(TMAX, BATCH);
    gather_kernel<<<g1, 128, 0, stream>>>(lp, labels, (float*)F);

    sweep_kernel<<<BATCH, 64, 0, stream>>>(F, lp, Tarr, Uarr, out);
}